// Round 6
// baseline (1521.961 us; speedup 1.0000x reference)
//
#include <hip/hip_runtime.h>
#include <hip/hip_cooperative_groups.h>

namespace cg = cooperative_groups;

#define N_ENT  30000
#define N_CON  29309
#define DIM    128
#define NBASIS 8
#define NREL   12
#define BATCH  256
#define LCON   50
#define SSEED  32
#define EDB    300000
#define ECON   200000
#define NTILE  938   // ceil(N_ENT/32)

#define NE4      ((N_CON * DIM) / 4)          // 937888 (exact)
#define NB_HIST  ((EDB + ECON + 255) / 256)   // 1954
// conv items (float4 units): emb NE4 + 3 bf16 mats 12288 + WuT 8192 + WiT 4096
#define NB_CONV  ((NE4 + 24576 + 255) / 256)  // 3760
#define NB_WCOMP ((N_ENT * 32) / 256)         // 3750
#define NB_PREP  (NB_HIST * 5)                // 9770: slot0=hist, slot1/2=conv, slot3/4=wcomp
#define CH_E     ((N_ENT + 63) / 64)          // 469 scan chunks (entities)
#define CH_C     ((N_CON + 63) / 64)          // 458 scan chunks (concepts)
#define CH_T     (CH_E + CH_C)                // 927
#define VB_SCAN  ((CH_T + 3) / 4)             // 232 (4 chunks per block, one per wave)
#define VB_XW    ((N_CON + 31) / 32)          // 916 xw tiles (32 rows each)
#define NB_RG8   ((N_ENT + 7) / 8)            // 3750
#define NB_GG8   ((N_CON + 7) / 8)            // 3664
#define NB_EDB   ((N_ENT + 31) / 32)          // 938
#define NB_ECON  ((N_CON + 31) / 32)          // 916
#define NB_SCORE (235 * 8)                    // score tiles: 235 x-blocks (4 nt each) x 8 b0-groups

typedef __attribute__((ext_vector_type(8)))  short bfrag8;
typedef __attribute__((ext_vector_type(16))) float facc16;

__device__ __forceinline__ unsigned short f2bf(float f) {
    unsigned int u = __float_as_uint(f);
    u += 0x7FFFu + ((u >> 16) & 1u);
    return (unsigned short)(u >> 16);
}
__device__ __forceinline__ float bf2f(unsigned int h) {
    return __uint_as_float(h << 16);
}
__device__ __forceinline__ unsigned int pk(float a, float b) {
    return (unsigned int)f2bf(a) | ((unsigned int)f2bf(b) << 16);
}

struct MP {
    const int *db_eidx, *db_etype, *con_eidx;
    const float *emb, *W, *A_db, *A_c, *Wu, *Wi, *basis, *comp;
    const int *seed_pad, *seed_lens, *concept_mask, *labels;
    const float *db_vec, *rec, *root, *bias, *gcn_b;
    const float *v_db, *v_c, *bu, *gw, *gb, *bi;
    const float *en_b, *info_b;
    int *cnt_e, *cnt_c, *ord_db, *ord_con, *rowptr_e, *rowptr_c, *elist_e, *elist_c;
    int *bsum_e, *bsum_c;
    unsigned short *emb_h, *Wt_h, *At_db_h, *At_c_h, *xw_h, *w_h;
    unsigned short *dbf_h, *conf_h, *uemb_h, *cone_h;
    float *WuT, *WiT, *dinv, *e_db, *e_con, *maskv, *rls, *ssqv;
    float *partM, *partS, *partQ, *escore, *out;
    int use_w;
};

// One cooperative kernel; phases separated by grid.sync(). All loops grid-strided.
__global__ __launch_bounds__(256, 6) void mega_kernel(MP P) {
    cg::grid_group grid = cg::this_grid();
    const int t = threadIdx.x;
    const int nbk = gridDim.x;
    const int wave = t >> 6, lane = t & 63;

    __shared__ float sc[NREL * NBASIS];
    __shared__ int   sscan[256];
    __shared__ float part4[4][32];
    __shared__ int   srow[SSEED];
    __shared__ int   crow[LCON];
    __shared__ float a_db[SSEED], a_con[LCON];
    __shared__ float du[DIM], cu[DIM], redf[DIM];
    __shared__ float redA[256], redB[256];

    const int* db_dst  = P.db_eidx + EDB;
    const int* con_dst = P.con_eidx + ECON;

    if (t < NREL * NBASIS) sc[t] = P.comp[t];
    __syncthreads();

    // ================= ph0: hist (x) conv (x) wcomp, modulo-interleaved =================
    for (int vb = blockIdx.x; vb < NB_PREP; vb += nbk) {
        int g = vb / 5, slot = vb % 5;
        if (slot == 0) {
            int e = g * 256 + t;
            if (e < EDB) {
                P.ord_db[e] = atomicAdd(P.cnt_e + db_dst[e], 1);
            } else if (e < EDB + ECON) {
                int ee = e - EDB;
                P.ord_con[ee] = atomicAdd(P.cnt_c + con_dst[ee], 1);
            }
        } else if (slot <= 2) {
            int cb = g * 2 + (slot - 1);
            if (cb < NB_CONV) {
                int i = cb * 256 + t;
                if (i < NE4) {
                    float4 v = ((const float4*)P.emb)[i];
                    *(uint2*)(P.emb_h + (size_t)i * 4) = make_uint2(pk(v.x, v.y), pk(v.z, v.w));
                } else {
                    int j = i - NE4;
                    if (j < 12288) {
                        int sel = j >> 12;
                        int jj = j & 4095;
                        const float* S = (sel == 0) ? P.W : ((sel == 1) ? P.A_db : P.A_c);
                        unsigned short* Dst = (sel == 0) ? P.Wt_h : ((sel == 1) ? P.At_db_h : P.At_c_h);
                        int o = jj * 4;
                        int n = o >> 7, k0 = o & 127;
                        unsigned int p0 = pk(S[(k0 + 0) * DIM + n], S[(k0 + 1) * DIM + n]);
                        unsigned int p1 = pk(S[(k0 + 2) * DIM + n], S[(k0 + 3) * DIM + n]);
                        *(uint2*)(Dst + n * DIM + k0) = make_uint2(p0, p1);
                    } else {
                        int j2 = j - 12288;
                        if (j2 < 8192) {
                            int o = j2 * 4;
                            int k = o >> 7, t0 = o & 127;
                            float4 vv;
                            vv.x = P.Wu[(t0 + 0) * (2 * DIM) + k];
                            vv.y = P.Wu[(t0 + 1) * (2 * DIM) + k];
                            vv.z = P.Wu[(t0 + 2) * (2 * DIM) + k];
                            vv.w = P.Wu[(t0 + 3) * (2 * DIM) + k];
                            *(float4*)(P.WuT + k * DIM + t0) = vv;
                        } else {
                            int j3 = j2 - 8192;
                            if (j3 < 4096) {
                                int o = j3 * 4;
                                int k = o >> 7, t0 = o & 127;
                                float4 vv;
                                vv.x = P.Wi[(t0 + 0) * DIM + k];
                                vv.y = P.Wi[(t0 + 1) * DIM + k];
                                vv.z = P.Wi[(t0 + 2) * DIM + k];
                                vv.w = P.Wi[(t0 + 3) * DIM + k];
                                *(float4*)(P.WiT + k * DIM + t0) = vv;
                            }
                        }
                    }
                }
            }
        } else {
            if (P.use_w) {
                int wb = g * 2 + (slot - 3);
                if (wb < NB_WCOMP) {
                    int i = wb * 256 + t;
                    int n = i >> 5, d4 = i & 31;
                    float4 bv[NBASIS];
#pragma unroll
                    for (int b = 0; b < NBASIS; ++b)
                        bv[b] = ((const float4*)(P.basis + ((size_t)b * N_ENT + n) * DIM))[d4];
#pragma unroll
                    for (int r = 0; r < NREL; ++r) {
                        float4 acc = make_float4(0.f, 0.f, 0.f, 0.f);
#pragma unroll
                        for (int b = 0; b < NBASIS; ++b) {
                            float c = sc[r * NBASIS + b];
                            acc.x += c * bv[b].x; acc.y += c * bv[b].y;
                            acc.z += c * bv[b].z; acc.w += c * bv[b].w;
                        }
                        *(uint2*)(P.w_h + ((size_t)n * NREL + r) * DIM + d4 * 4) =
                            make_uint2(pk(acc.x, acc.y), pk(acc.z, acc.w));
                    }
                }
            }
        }
    }
    grid.sync();

    // ================= ph1a: wave-level chunk scans (+xw MFMA on leftover blocks) =================
    for (int vb = blockIdx.x; vb < VB_SCAN + VB_XW; vb += nbk) {
        if (vb < VB_SCAN) {
            int c = vb * 4 + wave;
            if (c < CH_T) {
                const int* cnt; int* rp; int* bs; int n; int cc;
                if (c < CH_E) { cnt = P.cnt_e; rp = P.rowptr_e; bs = P.bsum_e; n = N_ENT; cc = c; }
                else          { cnt = P.cnt_c; rp = P.rowptr_c; bs = P.bsum_c; n = N_CON; cc = c - CH_E; }
                int idx = cc * 64 + lane;
                int x = (idx < n) ? cnt[idx] : 0;
                int incl = x;
#pragma unroll
                for (int off = 1; off < 64; off <<= 1) {
                    int y = __shfl_up(incl, off, 64);
                    if (lane >= off) incl += y;
                }
                if (idx < n) rp[idx] = incl - x;
                if (lane == 63) bs[cc] = incl;
            }
        } else {
            // xw_h = bf16(emb @ W): tile of 32 rows, 4 waves cover 128 cols
            int tile = vb - VB_SCAN;
            int m0 = tile * 32;
            int n0 = wave * 32;
            int am = lane & 31, ak = (lane >> 5) * 8;
            int mrow = m0 + am;
            bool mv = mrow < N_CON;
            const unsigned short* Ar = P.emb_h + (size_t)mrow * DIM + ak;
            const unsigned short* Br = P.Wt_h + (size_t)(n0 + am) * DIM + ak;
            facc16 acc;
#pragma unroll
            for (int r = 0; r < 16; ++r) acc[r] = 0.f;
#pragma unroll
            for (int s = 0; s < 8; ++s) {
                bfrag8 a;
#pragma unroll
                for (int j = 0; j < 8; ++j) a[j] = 0;
                if (mv) a = *(const bfrag8*)(Ar + s * 16);
                bfrag8 b = *(const bfrag8*)(Br + s * 16);
                acc = __builtin_amdgcn_mfma_f32_32x32x16_bf16(a, b, acc, 0, 0, 0);
            }
            int col = lane & 31;
            int g4 = (lane >> 5) * 4;
#pragma unroll
            for (int r = 0; r < 16; ++r) {
                int m = m0 + (r & 3) + ((r >> 2) << 3) + g4;
                if (m < N_CON) P.xw_h[(size_t)m * DIM + n0 + col] = f2bf(acc[r]);
            }
        }
    }
    grid.sync();

    // ================= ph1b: block-sum scans (blocks 0,1) + dinv (others) =================
    if (blockIdx.x < 2) {
        int n = (blockIdx.x == 0) ? CH_E : CH_C;
        int* bs = (blockIdx.x == 0) ? P.bsum_e : P.bsum_c;
        int* rp_top = (blockIdx.x == 0) ? (P.rowptr_e + N_ENT) : (P.rowptr_c + N_CON);
        int a0 = (2 * t < n) ? bs[2 * t] : 0;
        int a1 = (2 * t + 1 < n) ? bs[2 * t + 1] : 0;
        int s = a0 + a1;
        sscan[t] = s;
        __syncthreads();
        for (int off = 1; off < 256; off <<= 1) {
            int v = (t >= off) ? sscan[t - off] : 0;
            __syncthreads();
            sscan[t] += v;
            __syncthreads();
        }
        int incl = sscan[t];
        int excl = incl - s;
        if (2 * t < n) bs[2 * t] = excl;
        if (2 * t + 1 < n) bs[2 * t + 1] = excl + a0;
        if (t == 255) *rp_top = incl;
    } else {
        for (int i = (blockIdx.x - 2) * 256 + t; i < N_CON; i += (nbk - 2) * 256)
            P.dinv[i] = rsqrtf((float)(P.cnt_c[i] + 1));
    }
    grid.sync();

    // ================= ph1c: add block offsets to local prefixes =================
    for (int vb = blockIdx.x; vb < VB_SCAN; vb += nbk) {
        int c = vb * 4 + wave;
        if (c < CH_T) {
            int* rp; const int* bs; int n; int cc;
            if (c < CH_E) { rp = P.rowptr_e; bs = P.bsum_e; n = N_ENT; cc = c; }
            else          { rp = P.rowptr_c; bs = P.bsum_c; n = N_CON; cc = c - CH_E; }
            int idx = cc * 64 + lane;
            if (idx < n) rp[idx] += bs[cc];
        }
    }
    grid.sync();

    // ================= ph2: scatter =================
    for (int vb = blockIdx.x; vb < NB_HIST; vb += nbk) {
        int e = vb * 256 + t;
        if (e < EDB) {
            int dst = db_dst[e];
            P.elist_e[P.rowptr_e[dst] + P.ord_db[e]] = P.db_eidx[e] | (P.db_etype[e] << 18);
        } else if (e < EDB + ECON) {
            int ee = e - EDB;
            int dst = con_dst[ee];
            P.elist_c[P.rowptr_c[dst] + P.ord_con[ee]] = P.con_eidx[ee];
        }
    }
    grid.sync();

    // ================= ph3: RGCN (x) GCN gathers (one row per 32-lane half-wave) =================
    for (int vb = blockIdx.x; vb < NB_RG8 * 2; vb += nbk) {
        int pair = vb >> 1;
        int half = t >> 5;
        int l32  = t & 31;
        if ((vb & 1) == 0) {
            int wid = pair * 8 + half;   // pair < 3750 -> wid < 30000 exact
            int beg = P.rowptr_e[wid], end = P.rowptr_e[wid + 1];
            float a0 = 0.f, a1 = 0.f, a2 = 0.f, a3 = 0.f;
            if (P.use_w) {
                int p = beg;
                for (; p + 3 < end; p += 4) {
                    int v0 = P.elist_e[p], v1 = P.elist_e[p + 1], v2 = P.elist_e[p + 2], v3 = P.elist_e[p + 3];
                    uint2 k0 = *(const uint2*)(P.w_h + ((size_t)(v0 & 0x3FFFF) * NREL + (v0 >> 18)) * DIM + l32 * 4);
                    uint2 k1 = *(const uint2*)(P.w_h + ((size_t)(v1 & 0x3FFFF) * NREL + (v1 >> 18)) * DIM + l32 * 4);
                    uint2 k2 = *(const uint2*)(P.w_h + ((size_t)(v2 & 0x3FFFF) * NREL + (v2 >> 18)) * DIM + l32 * 4);
                    uint2 k3 = *(const uint2*)(P.w_h + ((size_t)(v3 & 0x3FFFF) * NREL + (v3 >> 18)) * DIM + l32 * 4);
                    a0 += bf2f(k0.x & 0xFFFF) + bf2f(k1.x & 0xFFFF) + bf2f(k2.x & 0xFFFF) + bf2f(k3.x & 0xFFFF);
                    a1 += bf2f(k0.x >> 16)    + bf2f(k1.x >> 16)    + bf2f(k2.x >> 16)    + bf2f(k3.x >> 16);
                    a2 += bf2f(k0.y & 0xFFFF) + bf2f(k1.y & 0xFFFF) + bf2f(k2.y & 0xFFFF) + bf2f(k3.y & 0xFFFF);
                    a3 += bf2f(k0.y >> 16)    + bf2f(k1.y >> 16)    + bf2f(k2.y >> 16)    + bf2f(k3.y >> 16);
                }
                for (; p < end; ++p) {
                    int v = P.elist_e[p];
                    uint2 k = *(const uint2*)(P.w_h + ((size_t)(v & 0x3FFFF) * NREL + (v >> 18)) * DIM + l32 * 4);
                    a0 += bf2f(k.x & 0xFFFF);
                    a1 += bf2f(k.x >> 16);
                    a2 += bf2f(k.y & 0xFFFF);
                    a3 += bf2f(k.y >> 16);
                }
            } else {
                for (int p = beg; p < end; ++p) {
                    int v = P.elist_e[p];
                    int src = v & 0x3FFFF, ty = v >> 18;
                    const float* c = sc + ty * NBASIS;
#pragma unroll
                    for (int b = 0; b < NBASIS; ++b) {
                        float4 bp = *(const float4*)(P.basis + ((size_t)b * N_ENT + src) * DIM + l32 * 4);
                        float cb = c[b];
                        a0 += cb * bp.x; a1 += cb * bp.y; a2 += cb * bp.z; a3 += cb * bp.w;
                    }
                }
            }
            float inv = 1.f / fmaxf((float)(end - beg), 1.f);
            size_t base = (size_t)wid * DIM + l32 * 4;
            int d0 = l32 * 4;
            float f0 = a0 * inv + P.root[base]     + P.bias[d0];
            float f1 = a1 * inv + P.root[base + 1] + P.bias[d0 + 1];
            float f2 = a2 * inv + P.root[base + 2] + P.bias[d0 + 2];
            float f3 = a3 * inv + P.root[base + 3] + P.bias[d0 + 3];
            *(uint2*)(P.dbf_h + base) = make_uint2(pk(f0, f1), pk(f2, f3));
        } else if (pair < NB_GG8) {
            int wid = pair * 8 + half;
            if (wid < N_CON) {
                int beg = P.rowptr_c[wid], end = P.rowptr_c[wid + 1];
                float a0 = 0.f, a1 = 0.f, a2 = 0.f, a3 = 0.f;
                int p = beg;
                for (; p + 3 < end; p += 4) {
                    int s0 = P.elist_c[p], s1 = P.elist_c[p + 1], s2 = P.elist_c[p + 2], s3 = P.elist_c[p + 3];
                    float n0 = P.dinv[s0], n1 = P.dinv[s1], n2 = P.dinv[s2], n3 = P.dinv[s3];
                    uint2 k0 = *(const uint2*)(P.xw_h + (size_t)s0 * DIM + l32 * 4);
                    uint2 k1 = *(const uint2*)(P.xw_h + (size_t)s1 * DIM + l32 * 4);
                    uint2 k2 = *(const uint2*)(P.xw_h + (size_t)s2 * DIM + l32 * 4);
                    uint2 k3 = *(const uint2*)(P.xw_h + (size_t)s3 * DIM + l32 * 4);
                    a0 += n0 * bf2f(k0.x & 0xFFFF) + n1 * bf2f(k1.x & 0xFFFF) + n2 * bf2f(k2.x & 0xFFFF) + n3 * bf2f(k3.x & 0xFFFF);
                    a1 += n0 * bf2f(k0.x >> 16)    + n1 * bf2f(k1.x >> 16)    + n2 * bf2f(k2.x >> 16)    + n3 * bf2f(k3.x >> 16);
                    a2 += n0 * bf2f(k0.y & 0xFFFF) + n1 * bf2f(k1.y & 0xFFFF) + n2 * bf2f(k2.y & 0xFFFF) + n3 * bf2f(k3.y & 0xFFFF);
                    a3 += n0 * bf2f(k0.y >> 16)    + n1 * bf2f(k1.y >> 16)    + n2 * bf2f(k2.y >> 16)    + n3 * bf2f(k3.y >> 16);
                }
                for (; p < end; ++p) {
                    int s = P.elist_c[p];
                    float nm = P.dinv[s];
                    uint2 k = *(const uint2*)(P.xw_h + (size_t)s * DIM + l32 * 4);
                    a0 += nm * bf2f(k.x & 0xFFFF);
                    a1 += nm * bf2f(k.x >> 16);
                    a2 += nm * bf2f(k.y & 0xFFFF);
                    a3 += nm * bf2f(k.y >> 16);
                }
                float dv = P.dinv[wid];
                uint2 ks = *(const uint2*)(P.xw_h + (size_t)wid * DIM + l32 * 4);
                size_t base = (size_t)wid * DIM + l32 * 4;
                int d0 = l32 * 4;
                float f0 = dv * a0 + dv * dv * bf2f(ks.x & 0xFFFF) + P.gcn_b[d0];
                float f1 = dv * a1 + dv * dv * bf2f(ks.x >> 16)    + P.gcn_b[d0 + 1];
                float f2 = dv * a2 + dv * dv * bf2f(ks.y & 0xFFFF) + P.gcn_b[d0 + 2];
                float f3 = dv * a3 + dv * dv * bf2f(ks.y >> 16)    + P.gcn_b[d0 + 3];
                *(uint2*)(P.conf_h + base) = make_uint2(pk(f0, f1), pk(f2, f3));
            }
        }
    }
    grid.sync();

    // ================= ph4: attention scores for ALL rows (db x con interleaved) =================
    for (int vb = blockIdx.x; vb < NB_EDB * 2; vb += nbk) {
        __syncthreads();   // part4 WAR between loop iterations
        int pair = vb >> 1;
        const unsigned short* feats; const unsigned short* At; const float* v; float* eo;
        int m0, nrow; bool act = true;
        if ((vb & 1) == 0) {
            feats = P.dbf_h;  At = P.At_db_h; v = P.v_db; eo = P.e_db;  m0 = pair * 32; nrow = N_ENT;
        } else {
            feats = P.conf_h; At = P.At_c_h;  v = P.v_c;  eo = P.e_con; m0 = pair * 32; nrow = N_CON;
            if (pair >= NB_ECON) act = false;
        }
        if (act) {
            int n0 = wave * 32;
            int am = lane & 31, ak = (lane >> 5) * 8;
            int mrow = m0 + am;
            bool mv = mrow < nrow;
            const unsigned short* Ar = feats + (size_t)mrow * DIM + ak;
            const unsigned short* Br = At + (size_t)(n0 + am) * DIM + ak;
            facc16 acc;
#pragma unroll
            for (int r = 0; r < 16; ++r) acc[r] = 0.f;
#pragma unroll
            for (int s = 0; s < 8; ++s) {
                bfrag8 a;
#pragma unroll
                for (int j = 0; j < 8; ++j) a[j] = 0;
                if (mv) a = *(const bfrag8*)(Ar + s * 16);
                bfrag8 b = *(const bfrag8*)(Br + s * 16);
                acc = __builtin_amdgcn_mfma_f32_32x32x16_bf16(a, b, acc, 0, 0, 0);
            }
            int col = lane & 31, g = lane >> 5;
            float vn = v[n0 + col];
#pragma unroll
            for (int r = 0; r < 16; ++r) {
                float x = tanhf(acc[r]) * vn;
#pragma unroll
                for (int off = 16; off >= 1; off >>= 1) x += __shfl_xor(x, off, 32);
                if (col == 0) {
                    int row = (r & 3) + ((r >> 2) << 3) + (g << 2);
                    part4[wave][row] = x;
                }
            }
        }
        __syncthreads();
        if (act && t < 32) {
            int m = m0 + t;
            if (m < nrow)
                eo[m] = part4[0][t] + part4[1][t] + part4[2][t] + part4[3][t];
        }
    }
    grid.sync();

    // ================= ph5: softmax + weighted sums + gated fusion per sample =================
    for (int vb = blockIdx.x; vb < BATCH; vb += nbk) {
        __syncthreads();
        int b = vb;
        int len = P.seed_lens[b];
        if (wave == 0) {
            float e = -1e30f;
            if (lane < SSEED) {
                int rv = P.seed_pad[b * SSEED + lane];
                srow[lane] = rv;
                if (lane < len) e = P.e_db[rv];
            }
            float m = e;
#pragma unroll
            for (int off = 16; off >= 1; off >>= 1) m = fmaxf(m, __shfl_xor(m, off, 32));
            float p = (lane < SSEED) ? __expf(e - m) : 0.f;
            float s = p;
#pragma unroll
            for (int off = 16; off >= 1; off >>= 1) s += __shfl_xor(s, off, 32);
            if (lane < SSEED) a_db[lane] = p / s;
        } else if (wave == 1) {
            float e = -1e30f;
            if (lane < LCON) {
                int rv = P.concept_mask[b * LCON + lane];
                crow[lane] = rv;
                if (rv != 0) e = P.e_con[rv];
            }
            float m = e;
#pragma unroll
            for (int off = 32; off >= 1; off >>= 1) m = fmaxf(m, __shfl_xor(m, off, 64));
            float p = (lane < LCON) ? __expf(e - m) : 0.f;
            float s = p;
#pragma unroll
            for (int off = 32; off >= 1; off >>= 1) s += __shfl_xor(s, off, 64);
            if (lane < LCON) a_con[lane] = p / s;
        }
        __syncthreads();
        if (t < DIM) {
            float acc = 0.f;
#pragma unroll
            for (int s = 0; s < SSEED; ++s)
                acc += a_db[s] * bf2f((unsigned int)P.dbf_h[(size_t)srow[s] * DIM + t]);
            du[t] = (len > 0) ? acc : 0.f;
        } else {
            int d = t - DIM;
            float acc = 0.f;
#pragma unroll
            for (int s = 0; s < LCON; ++s)
                acc += a_con[s] * bf2f((unsigned int)P.conf_h[(size_t)crow[s] * DIM + d]);
            cu[d] = acc;
        }
        __syncthreads();
        if (t < DIM) {
            float u = P.bu[t];
            for (int k = 0; k < DIM; ++k) u += cu[k] * P.WuT[k * DIM + t];
            for (int k = 0; k < DIM; ++k) u += du[k] * P.WuT[(DIM + k) * DIM + t];
            redf[t] = u * P.gw[t];
        }
        __syncthreads();
        for (int s2 = 64; s2 > 0; s2 >>= 1) {
            if (t < s2) redf[t] += redf[t + s2];
            __syncthreads();
        }
        if (t < DIM) {
            float gate = 1.f / (1.f + __expf(-(redf[0] + P.gb[0])));
            P.uemb_h[b * DIM + t] = f2bf(gate * du[t] + (1.f - gate) * cu[t]);
            float ce = P.bi[t];
            for (int k = 0; k < DIM; ++k) ce += cu[k] * P.WiT[k * DIM + t];
            P.cone_h[b * DIM + t] = f2bf(ce);
        }
        if (t == 0) P.maskv[b] = (len > 0) ? 1.f : 0.f;
    }
    grid.sync();

    // ================= ph6: scoring GEMMs (MFMA) + CE/ssq partials =================
    for (int vb = blockIdx.x; vb < NB_SCORE; vb += nbk) {
        int nt = (vb % 235) * 4 + wave;
        int b0 = (vb / 235) * 32;
        if (nt < NTILE) {
            int n0 = nt * 32;
            int am = lane & 31, ak = (lane >> 5) * 8;
            int nb2 = n0 + am;
            bool bvalid = nb2 < N_ENT;
            const unsigned short* Au = P.uemb_h + (size_t)(b0 + am) * DIM + ak;
            const unsigned short* Ac = P.cone_h + (size_t)(b0 + am) * DIM + ak;
            const unsigned short* Bp = P.dbf_h + (size_t)nb2 * DIM + ak;
            facc16 accE, accD;
#pragma unroll
            for (int r = 0; r < 16; ++r) { accE[r] = 0.f; accD[r] = 0.f; }
#pragma unroll
            for (int s = 0; s < 8; ++s) {
                bfrag8 au = *(const bfrag8*)(Au + s * 16);
                bfrag8 ac = *(const bfrag8*)(Ac + s * 16);
                bfrag8 bb;
#pragma unroll
                for (int j = 0; j < 8; ++j) bb[j] = 0;
                if (bvalid) bb = *(const bfrag8*)(Bp + s * 16);
                accE = __builtin_amdgcn_mfma_f32_32x32x16_bf16(au, bb, accE, 0, 0, 0);
                accD = __builtin_amdgcn_mfma_f32_32x32x16_bf16(ac, bb, accD, 0, 0, 0);
            }
            int col = lane & 31;
            int n = n0 + col;
            bool nv = n < N_ENT;
            float enb = nv ? P.en_b[n] : 0.f;
            float inb = nv ? P.info_b[n] : 0.f;
            int g4 = (lane >> 5) * 4;
#pragma unroll
            for (int r = 0; r < 16; ++r) {
                int b = b0 + (r & 3) + ((r >> 2) << 3) + g4;
                float e = accE[r] + enb;
                if (nv) __builtin_nontemporal_store(e, &P.escore[(size_t)b * N_ENT + n]);
                float ev = nv ? e : -1e30f;
                float mx = ev;
#pragma unroll
                for (int off = 16; off >= 1; off >>= 1) mx = fmaxf(mx, __shfl_xor(mx, off, 64));
                float ex = nv ? __expf(e - mx) : 0.f;
                float sm = ex;
#pragma unroll
                for (int off = 16; off >= 1; off >>= 1) sm += __shfl_xor(sm, off, 64);
                float d = nv ? (accD[r] + inb - P.db_vec[(size_t)b * N_ENT + n]) : 0.f;
                float q = d * d;
#pragma unroll
                for (int off = 16; off >= 1; off >>= 1) q += __shfl_xor(q, off, 64);
                if (col == 0) {
                    P.partM[(size_t)b * NTILE + nt] = mx;
                    P.partS[(size_t)b * NTILE + nt] = sm;
                    P.partQ[(size_t)b * NTILE + nt] = q;
                }
            }
        }
    }
    grid.sync();

    // ================= ph7: CE finalize per sample =================
    for (int vb = blockIdx.x; vb < BATCH; vb += nbk) {
        __syncthreads();
        int b = vb;
        const float* pm = P.partM + (size_t)b * NTILE;
        const float* ps = P.partS + (size_t)b * NTILE;
        const float* pq = P.partQ + (size_t)b * NTILE;
        float mx = -1e30f;
        for (int i = t; i < NTILE; i += 256) mx = fmaxf(mx, pm[i]);
        redA[t] = mx;
        __syncthreads();
        for (int s2 = 128; s2 > 0; s2 >>= 1) {
            if (t < s2) redA[t] = fmaxf(redA[t], redA[t + s2]);
            __syncthreads();
        }
        float M = redA[0];
        __syncthreads();
        float s = 0.f, q = 0.f;
        for (int i = t; i < NTILE; i += 256) {
            s += ps[i] * __expf(pm[i] - M);
            q += pq[i];
        }
        redA[t] = s; redB[t] = q;
        __syncthreads();
        for (int s2 = 128; s2 > 0; s2 >>= 1) {
            if (t < s2) { redA[t] += redA[t + s2]; redB[t] += redB[t + s2]; }
            __syncthreads();
        }
        if (t == 0) {
            float lse = M + logf(redA[0]);
            float ce  = -(P.escore[(size_t)b * N_ENT + P.labels[b]] - lse);
            P.rls[b]  = ce * P.rec[b];
            P.ssqv[b] = redB[0];
        }
    }
    grid.sync();

    // ================= ph8: final scalar reduction =================
    if (blockIdx.x == 0) {
        redA[t] = P.rls[t];
        redB[t] = P.ssqv[t] * P.maskv[t];
        __syncthreads();
        for (int s2 = 128; s2 > 0; s2 >>= 1) {
            if (t < s2) { redA[t] += redA[t + s2]; redB[t] += redB[t + s2]; }
            __syncthreads();
        }
        if (t == 0) {
            float rec_loss = redA[0];
            float info = redB[0] / (float)BATCH;
            P.out[0] = rec_loss + 0.025f * info;
            P.out[1 + (size_t)BATCH * N_ENT] = rec_loss;
        }
    }
}

// ============================ launch
extern "C" void kernel_launch(void* const* d_in, const int* in_sizes, int n_in,
                              void* d_out, int out_size, void* d_ws, size_t ws_size,
                              hipStream_t stream) {
    (void)in_sizes; (void)n_in; (void)out_size;
    MP P;
    P.concept_mask = (const int*)d_in[0];
    P.seed_pad     = (const int*)d_in[1];
    P.seed_lens    = (const int*)d_in[2];
    P.db_eidx      = (const int*)d_in[3];
    P.db_etype     = (const int*)d_in[4];
    P.con_eidx     = (const int*)d_in[5];
    P.db_vec       = (const float*)d_in[6];
    P.labels       = (const int*)d_in[7];
    P.rec          = (const float*)d_in[8];
    P.emb          = (const float*)d_in[9];
    P.basis        = (const float*)d_in[10];
    P.comp         = (const float*)d_in[11];
    P.root         = (const float*)d_in[12];
    P.bias         = (const float*)d_in[13];
    P.W            = (const float*)d_in[14];
    P.gcn_b        = (const float*)d_in[15];
    P.A_c          = (const float*)d_in[16];
    P.v_c          = (const float*)d_in[17];
    P.A_db         = (const float*)d_in[18];
    P.v_db         = (const float*)d_in[19];
    P.Wu           = (const float*)d_in[20];
    P.bu           = (const float*)d_in[21];
    P.gw           = (const float*)d_in[22];
    P.gb           = (const float*)d_in[23];
    P.Wi           = (const float*)d_in[24];
    P.bi           = (const float*)d_in[25];
    P.info_b       = (const float*)d_in[26];
    P.en_b         = (const float*)d_in[27];

    float* ws = (float*)d_ws;
    size_t off = 0;
    auto alloc = [&](size_t n) { float* p = ws + off; off += (n + 255) & ~(size_t)255; return p; };
    P.dinv   = alloc(N_CON);
    P.maskv  = alloc(BATCH);
    P.rls    = alloc(BATCH);
    P.ssqv   = alloc(BATCH);
    P.partM  = alloc((size_t)BATCH * NTILE);
    P.partS  = alloc((size_t)BATCH * NTILE);
    P.partQ  = alloc((size_t)BATCH * NTILE);
    P.cnt_e  = (int*)alloc(N_ENT + N_CON);     // contiguous for one memset
    P.cnt_c  = P.cnt_e + N_ENT;
    P.rowptr_e = (int*)alloc(N_ENT + 1);
    P.rowptr_c = (int*)alloc(N_CON + 1);
    P.bsum_e = (int*)alloc(512);
    P.bsum_c = (int*)alloc(512);
    P.ord_db = (int*)alloc(EDB);
    P.ord_con = (int*)alloc(ECON);
    P.elist_e = (int*)alloc(EDB);
    P.elist_c = (int*)alloc(ECON);
    P.dbf_h  = (unsigned short*)alloc((size_t)N_ENT * DIM / 2);
    P.conf_h = (unsigned short*)alloc((size_t)N_CON * DIM / 2 + 128);
    P.xw_h   = (unsigned short*)alloc((size_t)N_CON * DIM / 2 + 128);
    P.emb_h  = (unsigned short*)alloc((size_t)N_CON * DIM / 2 + 128);
    P.Wt_h   = (unsigned short*)alloc(DIM * DIM / 2);
    P.uemb_h = (unsigned short*)alloc(BATCH * DIM / 2);
    P.cone_h = (unsigned short*)alloc(BATCH * DIM / 2);
    P.e_db   = alloc(N_ENT);
    P.e_con  = alloc(N_CON);
    P.At_db_h = (unsigned short*)alloc(DIM * DIM / 2);
    P.At_c_h  = (unsigned short*)alloc(DIM * DIM / 2);
    P.WuT    = alloc(2 * DIM * DIM);
    P.WiT    = alloc(DIM * DIM);
    size_t w_elems = ((size_t)NREL * N_ENT * DIM) / 2;   // bf16 in float-units
    P.use_w = (off + w_elems) * sizeof(float) <= ws_size;
    P.w_h   = (unsigned short*)(ws + off);

    float* out = (float*)d_out;
    P.out    = out;
    P.escore = out + 1;

    (void)hipMemsetAsync(P.cnt_e, 0, (N_ENT + N_CON) * sizeof(int), stream);

    static int coopGrid = 0;
    if (coopGrid == 0) {
        int nbk = 0;
        if (hipOccupancyMaxActiveBlocksPerMultiprocessor(&nbk, (const void*)mega_kernel, 256, 0)
                != hipSuccess || nbk <= 0)
            nbk = 4;
        int ncu = 256;
        hipDeviceProp_t prop;
        if (hipGetDeviceProperties(&prop, 0) == hipSuccess && prop.multiProcessorCount > 0)
            ncu = prop.multiProcessorCount;
        coopGrid = nbk * ncu;
        if (coopGrid > 2048) coopGrid = 2048;
        if (coopGrid < 64) coopGrid = 64;
    }

    void* args[] = { (void*)&P };
    (void)hipLaunchCooperativeKernel((const void*)mega_kernel, dim3(coopGrid), dim3(256),
                                     args, 0, stream);
}